// Round 4
// baseline (272.921 us; speedup 1.0000x reference)
//
#include <hip/hip_runtime.h>
#include <math.h>

// SkipGram negative-sampling loss.
// loss = -( sum_n logsig(t_n . c_n) + logsig( -sum_k t_n . neg_{n,k} ) ) / N
// Uses dot(t, sum_k neg_k) == sum_k dot(t, neg_k) to do ONE neg dot per pair.
//
// Layout: one 64-lane wave per pair; lane l owns elements [2l, 2l+1] of D=128.
// Each row read = 64 lanes x float2 = 512B coalesced.

#define BLOCK 256
#define GRID  2048                 // 8192 waves = 32 waves/CU -> full occupancy
#define WPB   (BLOCK / 64)         // waves per block

__device__ __forceinline__ float log_sigmoidf(float x) {
    // stable: min(x,0) - log1p(exp(-|x|))
    return fminf(x, 0.0f) - log1pf(__expf(-fabsf(x)));
}

__global__ __launch_bounds__(BLOCK) void sg_main(
        const int* __restrict__ tgt,      // [N]
        const int* __restrict__ ctx,      // [N]
        const int* __restrict__ neg,      // [N,5]
        const float* __restrict__ Wh,     // [V,128]
        const float* __restrict__ Wo,     // [V,128]
        float* __restrict__ partials,     // [GRID]
        int N)
{
    const int lane  = threadIdx.x & 63;
    const int wib   = threadIdx.x >> 6;          // wave in block
    const int gwave = blockIdx.x * WPB + wib;
    const int nwaves = gridDim.x * WPB;

    float acc = 0.0f;

    for (int n = gwave; n < N; n += nwaves) {
        // wave-uniform index loads -> compiler scalarizes to s_load
        const int it = tgt[n];
        const int ic = ctx[n];

        const float2 t2 = ((const float2*)(Wh + (size_t)it * 128))[lane];
        const float2 c2 = ((const float2*)(Wo + (size_t)ic * 128))[lane];

        float nx = 0.0f, ny = 0.0f;
        #pragma unroll
        for (int k = 0; k < 5; ++k) {
            const int in_ = neg[n * 5 + k];
            const float2 e = ((const float2*)(Wo + (size_t)in_ * 128))[lane];
            nx += e.x;
            ny += e.y;
        }

        float p = fmaf(t2.x, c2.x, t2.y * c2.y);   // partial pos dot
        float q = fmaf(t2.x, nx,   t2.y * ny);     // partial (summed) neg dot

        // 64-lane butterfly reduce (both values)
        #pragma unroll
        for (int off = 32; off; off >>= 1) {
            p += __shfl_xor(p, off, 64);
            q += __shfl_xor(q, off, 64);
        }

        if (lane == 0)
            acc += log_sigmoidf(p) + log_sigmoidf(-q);
    }

    __shared__ float s[WPB];
    if (lane == 0) s[wib] = acc;
    __syncthreads();
    if (threadIdx.x == 0) {
        float b = 0.0f;
        #pragma unroll
        for (int w = 0; w < WPB; ++w) b += s[w];
        partials[blockIdx.x] = b;     // every block writes -> no ws init needed
    }
}

__global__ __launch_bounds__(256) void sg_final(
        const float* __restrict__ partials,
        float* __restrict__ out, int nPart, float invN)
{
    __shared__ float s[256];
    float v = 0.0f;
    for (int i = threadIdx.x; i < nPart; i += 256) v += partials[i];
    s[threadIdx.x] = v;
    __syncthreads();
    for (int off = 128; off; off >>= 1) {
        if (threadIdx.x < off) s[threadIdx.x] += s[threadIdx.x + off];
        __syncthreads();
    }
    if (threadIdx.x == 0) out[0] = -s[0] * invN;
}

extern "C" void kernel_launch(void* const* d_in, const int* in_sizes, int n_in,
                              void* d_out, int out_size, void* d_ws, size_t ws_size,
                              hipStream_t stream)
{
    const int*   tgt = (const int*)d_in[0];   // targets_1_pos        [N] int32
    const int*   ctx = (const int*)d_in[1];   // contexts_1_pos       [N] int32
    const int*   neg = (const int*)d_in[2];   // contexts_0_pos_samples [N,5] int32
    const float* Wh  = (const float*)d_in[3]; // W_hidden  [V,128] f32
    const float* Wo  = (const float*)d_in[4]; // W_output  [V,128] f32
    float* out = (float*)d_out;

    const int N = in_sizes[0];
    float* partials = (float*)d_ws;           // needs GRID*4 = 8 KB scratch

    sg_main<<<GRID, BLOCK, 0, stream>>>(tgt, ctx, neg, Wh, Wo, partials, N);
    sg_final<<<1, 256, 0, stream>>>(partials, out, GRID, 1.0f / (float)N);
}

// Round 5
// 249.420 us; speedup vs baseline: 1.0942x; 1.0942x over previous
//
#include <hip/hip_runtime.h>
#include <math.h>

// SkipGram negative-sampling loss.
// loss = -( sum_n logsig(t_n . c_n) + logsig( -sum_k t_n . neg_{n,k} ) ) / N
// Uses dot(t, sum_k neg_k) == sum_k dot(t, neg_k): ONE neg dot per pair.
//
// Layout: 16 lanes per pair (4 pairs per wave). Lane owns 8 of D=128 elements
// as 2x float4 -> each row read is 16 lanes x 32B = 512B contiguous.
// Butterfly reduce is only 4 steps and serves 4 pairs per instruction.

#define BLOCK 256
#define GRID  2048                 // 8192 waves; each wave sweeps 4 pairs/iter
#define WPB   (BLOCK / 64)

__device__ __forceinline__ float log_sigmoidf(float x) {
    // stable: min(x,0) - log1p(exp(-|x|))
    return fminf(x, 0.0f) - log1pf(__expf(-fabsf(x)));
}

__device__ __forceinline__ float dot8(float4 a0, float4 a1, float4 b0, float4 b1) {
    float r = a0.x * b0.x;
    r = fmaf(a0.y, b0.y, r);
    r = fmaf(a0.z, b0.z, r);
    r = fmaf(a0.w, b0.w, r);
    r = fmaf(a1.x, b1.x, r);
    r = fmaf(a1.y, b1.y, r);
    r = fmaf(a1.z, b1.z, r);
    r = fmaf(a1.w, b1.w, r);
    return r;
}

__global__ __launch_bounds__(BLOCK) void sg_main(
        const int* __restrict__ tgt,      // [N]
        const int* __restrict__ ctx,      // [N]
        const int* __restrict__ neg,      // [N,5]
        const float* __restrict__ Wh,     // [V,128]
        const float* __restrict__ Wo,     // [V,128]
        float* __restrict__ partials,     // [GRID]
        int N)
{
    const int tid  = threadIdx.x;
    const int lane = tid & 63;
    const int sl   = lane & 15;          // lane within 16-lane group
    const int sub  = lane >> 4;          // group within wave: 0..3
    const int wib  = tid >> 6;
    const int gwave  = blockIdx.x * WPB + wib;
    const int stride = GRID * WPB * 4;   // pairs per sweep

    const float4* __restrict__ Wh4 = (const float4*)Wh;
    const float4* __restrict__ Wo4 = (const float4*)Wo;

    float acc = 0.0f;

    for (int n = gwave * 4 + sub; n < N; n += stride) {
        const int it = tgt[n];
        const int ic = ctx[n];

        const float4* tp = Wh4 + ((size_t)it << 5);   // 32 float4 per row
        const float4* cp = Wo4 + ((size_t)ic << 5);
        const float4 t0 = tp[sl], t1 = tp[sl + 16];
        const float4 c0 = cp[sl], c1 = cp[sl + 16];

        float4 s0 = {0.f, 0.f, 0.f, 0.f};
        float4 s1 = {0.f, 0.f, 0.f, 0.f};
        #pragma unroll
        for (int k = 0; k < 5; ++k) {
            const int in_ = neg[n * 5 + k];
            const float4* ep = Wo4 + ((size_t)in_ << 5);
            const float4 e0 = ep[sl], e1 = ep[sl + 16];
            s0.x += e0.x; s0.y += e0.y; s0.z += e0.z; s0.w += e0.w;
            s1.x += e1.x; s1.y += e1.y; s1.z += e1.z; s1.w += e1.w;
        }

        float p = dot8(t0, t1, c0, c1);   // pos dot partial (8 elems)
        float q = dot8(t0, t1, s0, s1);   // summed-neg dot partial

        // 16-lane butterfly: every lane in the group ends with the full dot.
        #pragma unroll
        for (int off = 8; off; off >>= 1) {
            p += __shfl_xor(p, off, 64);
            q += __shfl_xor(q, off, 64);
        }

        if (sl == 0)
            acc += log_sigmoidf(p) + log_sigmoidf(-q);
    }

    // 16 group-leaders per block hold partial sums.
    __shared__ float s[BLOCK / 16];
    if (sl == 0) s[tid >> 4] = acc;
    __syncthreads();
    if (tid == 0) {
        float b = 0.0f;
        #pragma unroll
        for (int i = 0; i < BLOCK / 16; ++i) b += s[i];
        partials[blockIdx.x] = b;         // every block writes -> no ws init
    }
}

__global__ __launch_bounds__(256) void sg_final(
        const float* __restrict__ partials,
        float* __restrict__ out, int nPart, float invN)
{
    __shared__ float s[256];
    float v = 0.0f;
    for (int i = threadIdx.x; i < nPart; i += 256) v += partials[i];
    s[threadIdx.x] = v;
    __syncthreads();
    for (int off = 128; off; off >>= 1) {
        if (threadIdx.x < off) s[threadIdx.x] += s[threadIdx.x + off];
        __syncthreads();
    }
    if (threadIdx.x == 0) out[0] = -s[0] * invN;
}

extern "C" void kernel_launch(void* const* d_in, const int* in_sizes, int n_in,
                              void* d_out, int out_size, void* d_ws, size_t ws_size,
                              hipStream_t stream)
{
    const int*   tgt = (const int*)d_in[0];   // targets_1_pos          [N] int32
    const int*   ctx = (const int*)d_in[1];   // contexts_1_pos         [N] int32
    const int*   neg = (const int*)d_in[2];   // contexts_0_pos_samples [N,5] int32
    const float* Wh  = (const float*)d_in[3]; // W_hidden  [V,128] f32
    const float* Wo  = (const float*)d_in[4]; // W_output  [V,128] f32
    float* out = (float*)d_out;

    const int N = in_sizes[0];
    float* partials = (float*)d_ws;           // GRID*4 = 8 KB scratch

    sg_main<<<GRID, BLOCK, 0, stream>>>(tgt, ctx, neg, Wh, Wo, partials, N);
    sg_final<<<1, 256, 0, stream>>>(partials, out, GRID, 1.0f / (float)N);
}

// Round 6
// 154.371 us; speedup vs baseline: 1.7679x; 1.6157x over previous
//
#include <hip/hip_runtime.h>
#include <math.h>

// SkipGram negative-sampling loss.
// loss = -( sum_n logsig(t_n . c_n) + logsig( -sum_k t_n . neg_{n,k} ) ) / N
// Uses dot(t, sum_k neg_k) == sum_k dot(t, neg_k): ONE neg dot per pair.
//
// R6: the gather path is line-count-bound (~3.6 TB/s L2-miss BW plateau across
// two kernel structures). Convert both tables to bf16 in d_ws (streaming,
// ~15us) so each row gather is 256B (4 lines) instead of 512B (8 lines).
// Numerics: elements ~±0.004, dots ~1e-4, loss ~1.386; bf16 table quantization
// shifts the loss by ~1e-5 << 2.77e-2 threshold.
//
// Layout: 16 lanes per pair (4 pairs/wave); lane owns 8 elems = one uint4
// (8 bf16). Row read = 16 lanes x 16B = 256B contiguous.

#define BLOCK 256
#define GRID  2048                 // 8192 waves = full wave-slot fill
#define WPB   (BLOCK / 64)

__device__ __forceinline__ float log_sigmoidf(float x) {
    // stable: min(x,0) - log1p(exp(-|x|))
    return fminf(x, 0.0f) - log1pf(__expf(-fabsf(x)));
}

// ---------------- f32 -> bf16 conversion (RTNE), streaming ----------------

__device__ __forceinline__ unsigned pk_bf16(float lo, float hi) {
    unsigned ul = __float_as_uint(lo);
    unsigned uh = __float_as_uint(hi);
    ul = (ul + 0x7fffu + ((ul >> 16) & 1u)) >> 16;          // low 16
    uh = (uh + 0x7fffu + ((uh >> 16) & 1u)) & 0xffff0000u;  // high 16
    return ul | uh;
}

__global__ __launch_bounds__(256) void cvt_bf16(
        const float* __restrict__ srcA, unsigned short* __restrict__ dstA, int nA,
        const float* __restrict__ srcB, unsigned short* __restrict__ dstB, int nB)
{
    const int chunksA = nA >> 3;                 // 8 elems per chunk
    const int total   = chunksA + (nB >> 3);
    for (int i = blockIdx.x * blockDim.x + threadIdx.x; i < total;
         i += gridDim.x * blockDim.x) {
        const float4* s; uint4* d; int j;
        if (i < chunksA) { s = (const float4*)srcA; d = (uint4*)dstA; j = i; }
        else             { s = (const float4*)srcB; d = (uint4*)dstB; j = i - chunksA; }
        const float4 f0 = s[2 * j], f1 = s[2 * j + 1];
        uint4 o;
        o.x = pk_bf16(f0.x, f0.y);
        o.y = pk_bf16(f0.z, f0.w);
        o.z = pk_bf16(f1.x, f1.y);
        o.w = pk_bf16(f1.z, f1.w);
        d[j] = o;
    }
}

// ---------------- main gather kernel, bf16 tables ----------------

__device__ __forceinline__ void unpk2(unsigned u, float& lo, float& hi) {
    lo = __uint_as_float(u << 16);
    hi = __uint_as_float(u & 0xffff0000u);
}

__global__ __launch_bounds__(BLOCK) void sg_main_bf16(
        const int* __restrict__ tgt,              // [N]
        const int* __restrict__ ctx,              // [N]
        const int* __restrict__ neg,              // [N,5]
        const unsigned short* __restrict__ Wh,    // [V,128] bf16
        const unsigned short* __restrict__ Wo,    // [V,128] bf16
        float* __restrict__ partials,             // [GRID]
        int N)
{
    const int tid  = threadIdx.x;
    const int lane = tid & 63;
    const int sl   = lane & 15;          // lane within 16-lane group
    const int sub  = lane >> 4;          // group within wave: 0..3
    const int wib  = tid >> 6;
    const int gwave  = blockIdx.x * WPB + wib;
    const int stride = GRID * WPB * 4;

    float acc = 0.0f;

    for (int n = gwave * 4 + sub; n < N; n += stride) {
        const int it = tgt[n];
        const int ic = ctx[n];

        // row = 128 bf16 = 16 uint4; lane sl takes uint4 #sl (8 elems)
        const uint4 tu = ((const uint4*)(Wh + ((size_t)it << 7)))[sl];
        const uint4 cu = ((const uint4*)(Wo + ((size_t)ic << 7)))[sl];

        float s0 = 0.f, s1 = 0.f, s2 = 0.f, s3 = 0.f,
              s4 = 0.f, s5 = 0.f, s6 = 0.f, s7 = 0.f;
        #pragma unroll
        for (int k = 0; k < 5; ++k) {
            const int in_ = neg[n * 5 + k];
            const uint4 eu = ((const uint4*)(Wo + ((size_t)in_ << 7)))[sl];
            float a, b;
            unpk2(eu.x, a, b); s0 += a; s1 += b;
            unpk2(eu.y, a, b); s2 += a; s3 += b;
            unpk2(eu.z, a, b); s4 += a; s5 += b;
            unpk2(eu.w, a, b); s6 += a; s7 += b;
        }

        float t0, t1, t2, t3, t4, t5, t6, t7;
        unpk2(tu.x, t0, t1); unpk2(tu.y, t2, t3);
        unpk2(tu.z, t4, t5); unpk2(tu.w, t6, t7);
        float c0, c1, c2, c3, c4, c5, c6, c7;
        unpk2(cu.x, c0, c1); unpk2(cu.y, c2, c3);
        unpk2(cu.z, c4, c5); unpk2(cu.w, c6, c7);

        float p = t0 * c0;
        p = fmaf(t1, c1, p); p = fmaf(t2, c2, p); p = fmaf(t3, c3, p);
        p = fmaf(t4, c4, p); p = fmaf(t5, c5, p); p = fmaf(t6, c6, p);
        p = fmaf(t7, c7, p);
        float q = t0 * s0;
        q = fmaf(t1, s1, q); q = fmaf(t2, s2, q); q = fmaf(t3, s3, q);
        q = fmaf(t4, s4, q); q = fmaf(t5, s5, q); q = fmaf(t6, s6, q);
        q = fmaf(t7, s7, q);

        // 16-lane butterfly (serves 4 pairs per instruction)
        #pragma unroll
        for (int off = 8; off; off >>= 1) {
            p += __shfl_xor(p, off, 64);
            q += __shfl_xor(q, off, 64);
        }

        if (sl == 0)
            acc += log_sigmoidf(p) + log_sigmoidf(-q);
    }

    __shared__ float s[BLOCK / 16];
    if (sl == 0) s[tid >> 4] = acc;
    __syncthreads();
    if (tid == 0) {
        float b = 0.0f;
        #pragma unroll
        for (int i = 0; i < BLOCK / 16; ++i) b += s[i];
        partials[blockIdx.x] = b;         // every block writes -> no ws init
    }
}

// ---------------- f32 fallback (round-5 kernel, used if ws too small) ------

__device__ __forceinline__ float dot8(float4 a0, float4 a1, float4 b0, float4 b1) {
    float r = a0.x * b0.x;
    r = fmaf(a0.y, b0.y, r); r = fmaf(a0.z, b0.z, r); r = fmaf(a0.w, b0.w, r);
    r = fmaf(a1.x, b1.x, r); r = fmaf(a1.y, b1.y, r); r = fmaf(a1.z, b1.z, r);
    r = fmaf(a1.w, b1.w, r);
    return r;
}

__global__ __launch_bounds__(BLOCK) void sg_main_f32(
        const int* __restrict__ tgt, const int* __restrict__ ctx,
        const int* __restrict__ neg,
        const float* __restrict__ Wh, const float* __restrict__ Wo,
        float* __restrict__ partials, int N)
{
    const int tid  = threadIdx.x;
    const int lane = tid & 63;
    const int sl   = lane & 15;
    const int sub  = lane >> 4;
    const int wib  = tid >> 6;
    const int gwave  = blockIdx.x * WPB + wib;
    const int stride = GRID * WPB * 4;

    const float4* __restrict__ Wh4 = (const float4*)Wh;
    const float4* __restrict__ Wo4 = (const float4*)Wo;

    float acc = 0.0f;
    for (int n = gwave * 4 + sub; n < N; n += stride) {
        const int it = tgt[n];
        const int ic = ctx[n];
        const float4* tp = Wh4 + ((size_t)it << 5);
        const float4* cp = Wo4 + ((size_t)ic << 5);
        const float4 t0 = tp[sl], t1 = tp[sl + 16];
        const float4 c0 = cp[sl], c1 = cp[sl + 16];

        float4 s0 = {0.f, 0.f, 0.f, 0.f};
        float4 s1 = {0.f, 0.f, 0.f, 0.f};
        #pragma unroll
        for (int k = 0; k < 5; ++k) {
            const int in_ = neg[n * 5 + k];
            const float4* ep = Wo4 + ((size_t)in_ << 5);
            const float4 e0 = ep[sl], e1 = ep[sl + 16];
            s0.x += e0.x; s0.y += e0.y; s0.z += e0.z; s0.w += e0.w;
            s1.x += e1.x; s1.y += e1.y; s1.z += e1.z; s1.w += e1.w;
        }

        float p = dot8(t0, t1, c0, c1);
        float q = dot8(t0, t1, s0, s1);
        #pragma unroll
        for (int off = 8; off; off >>= 1) {
            p += __shfl_xor(p, off, 64);
            q += __shfl_xor(q, off, 64);
        }
        if (sl == 0)
            acc += log_sigmoidf(p) + log_sigmoidf(-q);
    }

    __shared__ float s[BLOCK / 16];
    if (sl == 0) s[tid >> 4] = acc;
    __syncthreads();
    if (tid == 0) {
        float b = 0.0f;
        #pragma unroll
        for (int i = 0; i < BLOCK / 16; ++i) b += s[i];
        partials[blockIdx.x] = b;
    }
}

// ---------------- finalize ----------------

__global__ __launch_bounds__(256) void sg_final(
        const float* __restrict__ partials,
        float* __restrict__ out, int nPart, float invN)
{
    __shared__ float s[256];
    float v = 0.0f;
    for (int i = threadIdx.x; i < nPart; i += 256) v += partials[i];
    s[threadIdx.x] = v;
    __syncthreads();
    for (int off = 128; off; off >>= 1) {
        if (threadIdx.x < off) s[threadIdx.x] += s[threadIdx.x + off];
        __syncthreads();
    }
    if (threadIdx.x == 0) out[0] = -s[0] * invN;
}

extern "C" void kernel_launch(void* const* d_in, const int* in_sizes, int n_in,
                              void* d_out, int out_size, void* d_ws, size_t ws_size,
                              hipStream_t stream)
{
    const int*   tgt = (const int*)d_in[0];   // targets_1_pos          [N] int32
    const int*   ctx = (const int*)d_in[1];   // contexts_1_pos         [N] int32
    const int*   neg = (const int*)d_in[2];   // contexts_0_pos_samples [N,5] int32
    const float* Wh  = (const float*)d_in[3]; // W_hidden  [V,128] f32
    const float* Wo  = (const float*)d_in[4]; // W_output  [V,128] f32
    float* out = (float*)d_out;

    const int N    = in_sizes[0];
    const int tblH = in_sizes[3];             // V*D elements
    const int tblO = in_sizes[4];

    float* partials = (float*)d_ws;           // GRID*4 = 8 KB
    const size_t off  = 8192;
    const size_t need = off + ((size_t)tblH + (size_t)tblO) * sizeof(unsigned short);

    if (ws_size >= need) {
        unsigned short* WhB = (unsigned short*)((char*)d_ws + off);
        unsigned short* WoB = WhB + tblH;
        cvt_bf16<<<2048, 256, 0, stream>>>(Wh, WhB, tblH, Wo, WoB, tblO);
        sg_main_bf16<<<GRID, BLOCK, 0, stream>>>(tgt, ctx, neg, WhB, WoB,
                                                 partials, N);
    } else {
        sg_main_f32<<<GRID, BLOCK, 0, stream>>>(tgt, ctx, neg, Wh, Wo,
                                                partials, N);
    }
    sg_final<<<1, 256, 0, stream>>>(partials, out, GRID, 1.0f / (float)N);
}